// Round 1
// baseline (90.193 us; speedup 1.0000x reference)
//
#include <hip/hip_runtime.h>

#define HWOUT 50176   // 224*224
#define NBLK_MAX 1024

__device__ __forceinline__ float fast_sigmoid(float x) {
    // sigmoid(x) = 1 / (1 + exp(-x)); exp via exp2, rcp via v_rcp_f32
    float t = __builtin_amdgcn_exp2f(-1.44269504088896340736f * x);
    return __builtin_amdgcn_rcpf(1.0f + t);
}
__device__ __forceinline__ float silu_f(float x) { return x * fast_sigmoid(x); }

// ---------------- Stage 1: silu(x) @ W1 + b1 -> silu -> partial column sums
// One wave = 64 lanes = 64 hidden columns. Rows staged via LDS (silu applied
// at stage time), padded 7->8 floats so each row is two aligned b128 reads.
__global__ __launch_bounds__(256) void k_stage1(const float* __restrict__ x,
                                                const float* __restrict__ W1,
                                                const float* __restrict__ b1,
                                                float* __restrict__ partial,
                                                int N, int nblk) {
    __shared__ float xs[256 * 8];
    const int t = threadIdx.x;
    const int lane = t & 63;
    const int wave = t >> 6;

    float w[7];
#pragma unroll
    for (int k = 0; k < 7; ++k) w[k] = W1[k * 64 + lane];
    const float bb = b1[lane];

    float acc = 0.0f;
    const long total = (long)N * 7;
    const int ntile = (N + 255) >> 8;

    for (int tile = blockIdx.x; tile < ntile; tile += nblk) {
        const long base = (long)tile * (256 * 7);
        __syncthreads();   // previous tile's reads done before overwrite
#pragma unroll
        for (int i = 0; i < 7; ++i) {
            int pos = i * 256 + t;           // 0..1791
            long g = base + pos;
            float v = (g < total) ? x[g] : 0.0f;
            int row = pos / 7;
            int col = pos - row * 7;
            xs[row * 8 + col] = silu_f(v);   // first silu fused into staging
        }
        __syncthreads();

        const int row0 = wave * 64;          // this wave's 64 rows in the tile
        const int rbase = tile * 256 + row0; // global row of r=0
#pragma unroll 4
        for (int r = 0; r < 64; ++r) {
            const float4* p = reinterpret_cast<const float4*>(&xs[(row0 + r) * 8]);
            float4 a = p[0];
            float4 b = p[1];   // b.w is pad, unused
            float d = bb;
            d = fmaf(a.x, w[0], d);
            d = fmaf(a.y, w[1], d);
            d = fmaf(a.z, w[2], d);
            d = fmaf(a.w, w[3], d);
            d = fmaf(b.x, w[4], d);
            d = fmaf(b.y, w[5], d);
            d = fmaf(b.z, w[6], d);
            float s = silu_f(d);
            acc += (rbase + r < N) ? s : 0.0f;  // mask tail rows
        }
    }

    // block reduce: 4 waves -> 64 column partials
    __syncthreads();
    xs[t] = acc;                     // t == wave*64 + lane
    __syncthreads();
    if (t < 64) {
        float s = xs[t] + xs[t + 64] + xs[t + 128] + xs[t + 192];
        partial[blockIdx.x * 64 + t] = s;
    }
}

// ---------------- Stage 2: reduce per-block partials -> m[64] (mean)
__global__ __launch_bounds__(256) void k_reduce(const float* __restrict__ partial,
                                                float* __restrict__ m,
                                                int nblk, float invN) {
    __shared__ float red[256];
    const int t = threadIdx.x;
    const int col = t & 63;
    const int chunk = t >> 6;
    float s = 0.0f;
    for (int r = chunk; r < nblk; r += 4) s += partial[r * 64 + col];
    red[t] = s;
    __syncthreads();
    if (t < 64)
        m[t] = (red[t] + red[t + 64] + red[t + 128] + red[t + 192]) * invN;
}

// ---------------- Stage 3: e = clamp(silu(m @ W2 + b2), 0, 1)
__global__ __launch_bounds__(256) void k_out(const float* __restrict__ m,
                                             const float* __restrict__ W2,
                                             const float* __restrict__ b2,
                                             float* __restrict__ out) {
    __shared__ float ml[64];
    const int t = threadIdx.x;
    if (t < 64) ml[t] = m[t];
    __syncthreads();
    const int j = blockIdx.x * 256 + t;     // grid is exactly HWOUT/256
    float acc = b2[j];
#pragma unroll
    for (int k = 0; k < 64; ++k)
        acc = fmaf(ml[k], W2[k * HWOUT + j], acc);
    float e = silu_f(acc);
    out[j] = fminf(fmaxf(e, 0.0f), 1.0f);
}

extern "C" void kernel_launch(void* const* d_in, const int* in_sizes, int n_in,
                              void* d_out, int out_size, void* d_ws, size_t ws_size,
                              hipStream_t stream) {
    const float* x  = (const float*)d_in[0];
    const float* W1 = (const float*)d_in[1];
    const float* b1 = (const float*)d_in[2];
    const float* W2 = (const float*)d_in[3];
    const float* b2 = (const float*)d_in[4];
    float* out = (float*)d_out;

    const int N = in_sizes[0] / 7;

    // scratch layout: partial[nblk][64] then m[64]
    long slots = (long)(ws_size / sizeof(float));
    long cap = slots - 64;
    int nblk = NBLK_MAX;
    if (cap < (long)nblk * 64) nblk = (int)(cap / 64);
    if (nblk < 1) nblk = 1;

    float* partial = (float*)d_ws;
    float* m = partial + (size_t)nblk * 64;

    k_stage1<<<nblk, 256, 0, stream>>>(x, W1, b1, partial, N, nblk);
    k_reduce<<<1, 256, 0, stream>>>(partial, m, nblk, 1.0f / (float)N);
    k_out<<<HWOUT / 256, 256, 0, stream>>>(m, W2, b2, out);
}

// Round 2
// 25.740 us; speedup vs baseline: 3.5039x; 3.5039x over previous
//
#include <hip/hip_runtime.h>
#include <hip/hip_bf16.h>

#define HWOUT 50176   // 224*224
#define NBLK  1024    // stage1 grid size == rows of partial[]
#define CHUNK 256     // rows staged per block iteration

typedef __attribute__((ext_vector_type(8))) short short8;
typedef __attribute__((ext_vector_type(4))) float f32x4;

__device__ __forceinline__ float fast_sigmoid(float x) {
    float t = __builtin_amdgcn_exp2f(-1.44269504088896340736f * x);
    return __builtin_amdgcn_rcpf(1.0f + t);
}
__device__ __forceinline__ float silu_f(float x) { return x * fast_sigmoid(x); }

__device__ __forceinline__ short to_bf16_bits(float f) {
    unsigned u = __builtin_bit_cast(unsigned, f);
    u += 0x7FFFu + ((u >> 16) & 1u);   // round-to-nearest-even
    return (short)(u >> 16);
}

// ---------------- Stage 1: partial[b][c] = sum over block's rows of
//                  silu( silu(x_row) . W1[:,c] + b1[c] )
// MFMA 16x16x32 bf16: A = 16 silu(x) rows (K=7 padded to 32, real data in
// lanes 0-15 only), B = W1 padded, held in registers for the whole kernel.
__global__ __launch_bounds__(256) void k_stage1(const float* __restrict__ x,
                                                const float* __restrict__ W1,
                                                const float* __restrict__ b1,
                                                float* __restrict__ partial,
                                                int N) {
    __shared__ short xs[CHUNK * 8];     // bf16 rows, 8-padded (16B each)
    __shared__ float red[4][64];
    const int t = threadIdx.x;
    const int lane = t & 63;
    const int wave = t >> 6;

    // B fragments: bf[g][j] = W1pad[k][g*16+c],  k = 8*(lane>>4)+j, zero k>=7
    const int krow = (lane >> 4) * 8;
    const int c = lane & 15;
    short8 bf[4];
    float bcol[4];
#pragma unroll
    for (int g = 0; g < 4; ++g) {
#pragma unroll
        for (int j = 0; j < 8; ++j) {
            int k = krow + j;
            float v = (k < 7) ? W1[k * 64 + g * 16 + c] : 0.0f;
            bf[g][j] = to_bf16_bits(v);
        }
        bcol[g] = b1[g * 16 + c];
    }

    float accf[4] = {0.0f, 0.0f, 0.0f, 0.0f};
    const int nchunk = (N + CHUNK - 1) / CHUNK;
    const short8 zero8 = {0, 0, 0, 0, 0, 0, 0, 0};
    const f32x4 zero4 = {0.0f, 0.0f, 0.0f, 0.0f};

    for (int ch = blockIdx.x; ch < nchunk; ch += NBLK) {
        const int row = ch * CHUNK + t;   // one staged row per thread
        __syncthreads();                  // prior compute done before overwrite
        {
            float v[7];
            if (row < N) {
#pragma unroll
                for (int k = 0; k < 7; ++k) v[k] = x[row * 7 + k];
            } else {
#pragma unroll
                for (int k = 0; k < 7; ++k) v[k] = 0.0f;
            }
            short8 p;
#pragma unroll
            for (int k = 0; k < 7; ++k) p[k] = to_bf16_bits(silu_f(v[k]));
            p[7] = 0;
            *reinterpret_cast<short8*>(&xs[t * 8]) = p;
        }
        __syncthreads();

        const bool full = (ch * CHUNK + CHUNK <= N);
        const int chbase = ch * CHUNK;
#pragma unroll
        for (int tt = 0; tt < 4; ++tt) {
            const int tile = wave * 4 + tt;
            // A fragment: lane l reads row tile*16 + (l&15); lanes >=16 are the
            // k=8..31 pad -> zero.
            short8 av = *reinterpret_cast<short8*>(&xs[(tile * 16 + c) * 8]);
            av = (lane < 16) ? av : zero8;
#pragma unroll
            for (int g = 0; g < 4; ++g) {
                f32x4 d = __builtin_amdgcn_mfma_f32_16x16x32_bf16(av, bf[g], zero4, 0, 0, 0);
                if (full) {
#pragma unroll
                    for (int r = 0; r < 4; ++r) accf[g] += silu_f(d[r] + bcol[g]);
                } else {
                    const int r0 = chbase + tile * 16 + (lane >> 4) * 4;
#pragma unroll
                    for (int r = 0; r < 4; ++r) {
                        float s = silu_f(d[r] + bcol[g]);
                        accf[g] += (r0 + r < N) ? s : 0.0f;
                    }
                }
            }
        }
    }

    // C layout: col = g*16 + (lane&15), rows split across lane>>4 -> xor-reduce
#pragma unroll
    for (int g = 0; g < 4; ++g) {
        accf[g] += __shfl_xor(accf[g], 16, 64);
        accf[g] += __shfl_xor(accf[g], 32, 64);
    }
    if (lane < 16) {
#pragma unroll
        for (int g = 0; g < 4; ++g) red[wave][g * 16 + lane] = accf[g];
    }
    __syncthreads();
    if (t < 64)
        partial[blockIdx.x * 64 + t] = red[0][t] + red[1][t] + red[2][t] + red[3][t];
}

// ---------------- Stage 2 (fused): every block redundantly reduces
// partial[NBLK][64] -> m[64], then computes its 256 outputs of
// clamp(silu(m @ W2 + b2), 0, 1).
__global__ __launch_bounds__(256) void k_out2(const float* __restrict__ partial,
                                              const float* __restrict__ W2,
                                              const float* __restrict__ b2,
                                              float* __restrict__ out,
                                              float invN) {
    __shared__ float4 red[256];
    __shared__ float ml[64];
    const int t = threadIdx.x;
    const int c4 = t & 15;     // float4 column group (cols 4*c4 .. 4*c4+3)
    const int grp = t >> 4;    // 0..15
    const float4* p4 = reinterpret_cast<const float4*>(partial);

    float4 s = {0.0f, 0.0f, 0.0f, 0.0f};
#pragma unroll 8
    for (int r = grp; r < NBLK; r += 16) {   // 64 coalesced float4 loads
        float4 v = p4[r * 16 + c4];
        s.x += v.x; s.y += v.y; s.z += v.z; s.w += v.w;
    }
    red[t] = s;
    __syncthreads();
    if (t < 16) {
        float4 a = {0.0f, 0.0f, 0.0f, 0.0f};
#pragma unroll
        for (int g = 0; g < 16; ++g) {
            float4 v = red[g * 16 + t];
            a.x += v.x; a.y += v.y; a.z += v.z; a.w += v.w;
        }
        ml[4 * t + 0] = a.x * invN;
        ml[4 * t + 1] = a.y * invN;
        ml[4 * t + 2] = a.z * invN;
        ml[4 * t + 3] = a.w * invN;
    }
    __syncthreads();

    const int j = blockIdx.x * 256 + t;   // grid is exactly HWOUT/256
    float acc = b2[j];
#pragma unroll
    for (int k4 = 0; k4 < 16; ++k4) {
        float4 mv = *reinterpret_cast<float4*>(&ml[k4 * 4]);
        acc = fmaf(mv.x, W2[(k4 * 4 + 0) * HWOUT + j], acc);
        acc = fmaf(mv.y, W2[(k4 * 4 + 1) * HWOUT + j], acc);
        acc = fmaf(mv.z, W2[(k4 * 4 + 2) * HWOUT + j], acc);
        acc = fmaf(mv.w, W2[(k4 * 4 + 3) * HWOUT + j], acc);
    }
    float e = silu_f(acc);
    out[j] = fminf(fmaxf(e, 0.0f), 1.0f);
}

extern "C" void kernel_launch(void* const* d_in, const int* in_sizes, int n_in,
                              void* d_out, int out_size, void* d_ws, size_t ws_size,
                              hipStream_t stream) {
    const float* x  = (const float*)d_in[0];
    const float* W1 = (const float*)d_in[1];
    const float* b1 = (const float*)d_in[2];
    const float* W2 = (const float*)d_in[3];
    const float* b2 = (const float*)d_in[4];
    float* out = (float*)d_out;

    const int N = in_sizes[0] / 7;
    float* partial = (float*)d_ws;   // NBLK*64 floats (ws verified >= 256KB in R1)

    k_stage1<<<NBLK, 256, 0, stream>>>(x, W1, b1, partial, N);
    k_out2<<<HWOUT / 256, 256, 0, stream>>>(partial, W2, b2, out, 1.0f / (float)N);
}